// Round 7
// baseline (249.783 us; speedup 1.0000x reference)
//
#include <hip/hip_runtime.h>
#include <math.h>

// ---------------------------------------------------------------------------
// GCN, atomic-free aggregation via per-call CSR (bucket by dst):
//   deg count (dst-partitioned) -> block scan(+dinv) -> add_offsets (fused
//   bsum scan) -> fill (dst-partitioned, XCD-local, u16)          [once]
//   per layer: G = (X@W)*dinv[row]  (GEMM, 64-row tile, 4x4 reg blocking)
//              y[i] = relu( dinv[i]*(G[i] + sum_{e: dst=i} G[src_e]) + b )
//   layers 1-2 emit bf16 activations; layer 3 fuses log_softmax (fp32 out).
// agg64: one wave per node; lane=(grp<<3)|sub, lane loads uint4 (8 bf16 cols),
//   8 lanes cover a 128B row, 8 edge rows per instruction (1KiB/instr);
//   partials merged with shfl_xor(8|16|32).
// agg40: 16-lane rows (uint2), 4 edge rows/instr, fused log_softmax.
// cidx is uint16 (N_NODES=50000 < 65536).
// NOTE: no hipMemsetAsync — rocclr fillBuffer took 45.9us for 195KB in-graph.
// ---------------------------------------------------------------------------

#define DF 64
#define TB 256
#define NPART 8

__device__ __forceinline__ unsigned short f2bf(float f) {
    union { float f; unsigned u; } c; c.f = f;
    unsigned u = c.u;
    return (unsigned short)((u + 0x7fffu + ((u >> 16) & 1u)) >> 16);   // RNE
}
__device__ __forceinline__ float bf2f(unsigned short h) {
    union { unsigned u; float f; } c; c.u = ((unsigned)h) << 16;
    return c.f;
}
__device__ __forceinline__ unsigned pk2bf(float lo, float hi) {
    return (unsigned)f2bf(lo) | ((unsigned)f2bf(hi) << 16);
}
__device__ __forceinline__ void acc_bf16x8(uint4 v, float* a) {
    a[0] += bf2f((unsigned short)(v.x & 0xffffu));
    a[1] += bf2f((unsigned short)(v.x >> 16));
    a[2] += bf2f((unsigned short)(v.y & 0xffffu));
    a[3] += bf2f((unsigned short)(v.y >> 16));
    a[4] += bf2f((unsigned short)(v.z & 0xffffu));
    a[5] += bf2f((unsigned short)(v.z >> 16));
    a[6] += bf2f((unsigned short)(v.w & 0xffffu));
    a[7] += bf2f((unsigned short)(v.w >> 16));
}
__device__ __forceinline__ void acc_bf16x4(uint2 v, float* a) {
    a[0] += bf2f((unsigned short)(v.x & 0xffffu));
    a[1] += bf2f((unsigned short)(v.x >> 16));
    a[2] += bf2f((unsigned short)(v.y & 0xffffu));
    a[3] += bf2f((unsigned short)(v.y >> 16));
}

__global__ void zero_int_kernel(int* __restrict__ p, int n) {
    int i = blockIdx.x * blockDim.x + threadIdx.x;
    if (i < n) p[i] = 0;
}

__global__ void count_deg_part_kernel(const int* __restrict__ dst, int* __restrict__ deg,
                                      int e, int psize) {
    const int p   = blockIdx.x & (NPART - 1);
    const int sl  = blockIdx.x / NPART;
    const int nsl = gridDim.x / NPART;
    const int lo = p * psize, hi = lo + psize;
    for (int i = sl * TB + threadIdx.x; i < e; i += nsl * TB) {
        int d = dst[i];
        if (d >= lo && d < hi) atomicAdd(&deg[d], 1);
    }
}

// per-block exclusive scan of deg -> ex (partial), block totals -> bsum; also dinv
__global__ void scan_block_kernel(const int* __restrict__ deg, int* __restrict__ ex,
                                  int* __restrict__ bsum, float* __restrict__ dinv, int n) {
    __shared__ int s[TB];
    const int t = threadIdx.x;
    const int i = blockIdx.x * TB + t;
    int v = (i < n) ? deg[i] : 0;
    if (i < n) dinv[i] = rsqrtf((float)(v + 1));   // +1 self-loop
    s[t] = v; __syncthreads();
#pragma unroll
    for (int o = 1; o < TB; o <<= 1) {
        int u = (t >= o) ? s[t - o] : 0;
        __syncthreads();
        s[t] += u;
        __syncthreads();
    }
    if (i < n) ex[i] = s[t] - v;
    if (t == TB - 1) bsum[blockIdx.x] = s[TB - 1];
}

// each block redundantly scans bsum (nb <= 256) in LDS, then offsets its slice
__global__ void add_offsets_kernel(int* __restrict__ ex, const int* __restrict__ bsum,
                                   int* __restrict__ cursor, int n, int nb) {
    __shared__ int s[TB];
    const int t = threadIdx.x;
    int v = (t < nb) ? bsum[t] : 0;
    s[t] = v; __syncthreads();
#pragma unroll
    for (int o = 1; o < TB; o <<= 1) {
        int u = (t >= o) ? s[t - o] : 0;
        __syncthreads();
        s[t] += u;
        __syncthreads();
    }
    const int boff = (blockIdx.x > 0) ? s[blockIdx.x - 1] : 0;
    const int i = blockIdx.x * TB + t;
    if (i < n) {
        int r = ex[i] + boff;
        ex[i] = r;
        cursor[i] = r;
    }
}

__global__ void fill_csr_part_kernel(const int* __restrict__ src, const int* __restrict__ dst,
                                     int* __restrict__ cursor,
                                     unsigned short* __restrict__ cidx, int e, int psize) {
    const int p   = blockIdx.x & (NPART - 1);
    const int sl  = blockIdx.x / NPART;
    const int nsl = gridDim.x / NPART;
    const int lo = p * psize, hi = lo + psize;
    for (int i = sl * TB + threadIdx.x; i < e; i += nsl * TB) {
        int d = dst[i];
        if (d >= lo && d < hi) {
            int pos = atomicAdd(&cursor[d], 1);
            cidx[pos] = (unsigned short)src[i];
        }
    }
}

// G[M x NC](bf16) = (X[M x 64] @ W[64 x NC]) * dinv[row].
// 64-row tile, block (16,16); thread (tx,ty) computes rows ty*4..+3, cols tx*4..+3.
template <int NC, typename TIN>
__global__ __launch_bounds__(256) void gemm_kernel(const TIN* __restrict__ X,
                                                   const float* __restrict__ W,
                                                   const float* __restrict__ dinv,
                                                   unsigned short* __restrict__ G, int M) {
    __shared__ float Ws[64 * NC];
    __shared__ float Xs[64][65];
    const int tx = threadIdx.x;            // 0..15
    const int ty = threadIdx.y;            // 0..15
    const int tid = ty * 16 + tx;
    for (int i = tid; i < 16 * NC; i += 256)
        ((float4*)Ws)[i] = ((const float4*)W)[i];
    const int row0 = blockIdx.x * 64;
    if (sizeof(TIN) == 4) {
        const float* Xf = (const float*)X;
#pragma unroll
        for (int i = tid; i < 1024; i += 256) {         // 64 rows x 16 float4
            int r = i >> 4, q = i & 15;
            float4 v = (row0 + r < M) ? ((const float4*)(Xf + (size_t)(row0 + r) * 64))[q]
                                      : make_float4(0.f, 0.f, 0.f, 0.f);
            Xs[r][q * 4 + 0] = v.x; Xs[r][q * 4 + 1] = v.y;
            Xs[r][q * 4 + 2] = v.z; Xs[r][q * 4 + 3] = v.w;
        }
    } else {
        const unsigned short* Xh = (const unsigned short*)X;
#pragma unroll
        for (int i = tid; i < 512; i += 256) {          // 64 rows x 8 uint4
            int r = i >> 3, s = i & 7;
            uint4 v = (row0 + r < M)
                        ? *(const uint4*)(Xh + (size_t)(row0 + r) * 64 + s * 8)
                        : make_uint4(0, 0, 0, 0);
            Xs[r][s * 8 + 0] = bf2f((unsigned short)(v.x & 0xffffu));
            Xs[r][s * 8 + 1] = bf2f((unsigned short)(v.x >> 16));
            Xs[r][s * 8 + 2] = bf2f((unsigned short)(v.y & 0xffffu));
            Xs[r][s * 8 + 3] = bf2f((unsigned short)(v.y >> 16));
            Xs[r][s * 8 + 4] = bf2f((unsigned short)(v.z & 0xffffu));
            Xs[r][s * 8 + 5] = bf2f((unsigned short)(v.z >> 16));
            Xs[r][s * 8 + 6] = bf2f((unsigned short)(v.w & 0xffffu));
            Xs[r][s * 8 + 7] = bf2f((unsigned short)(v.w >> 16));
        }
    }
    __syncthreads();
    if (tx * 4 >= NC) return;                           // idle cols (NC=40)
    float acc[4][4];
#pragma unroll
    for (int i = 0; i < 4; ++i)
#pragma unroll
        for (int j = 0; j < 4; ++j) acc[i][j] = 0.f;
#pragma unroll
    for (int k = 0; k < 64; ++k) {
        float4 w = ((const float4*)(Ws + (size_t)k * NC))[tx];
        float x0 = Xs[ty * 4 + 0][k];
        float x1 = Xs[ty * 4 + 1][k];
        float x2 = Xs[ty * 4 + 2][k];
        float x3 = Xs[ty * 4 + 3][k];
        acc[0][0] += x0 * w.x; acc[0][1] += x0 * w.y; acc[0][2] += x0 * w.z; acc[0][3] += x0 * w.w;
        acc[1][0] += x1 * w.x; acc[1][1] += x1 * w.y; acc[1][2] += x1 * w.z; acc[1][3] += x1 * w.w;
        acc[2][0] += x2 * w.x; acc[2][1] += x2 * w.y; acc[2][2] += x2 * w.z; acc[2][3] += x2 * w.w;
        acc[3][0] += x3 * w.x; acc[3][1] += x3 * w.y; acc[3][2] += x3 * w.z; acc[3][3] += x3 * w.w;
    }
#pragma unroll
    for (int i = 0; i < 4; ++i) {
        const int row = row0 + ty * 4 + i;
        if (row < M) {
            const float di = dinv[row];
            ushort4 o;
            o.x = f2bf(acc[i][0] * di); o.y = f2bf(acc[i][1] * di);
            o.z = f2bf(acc[i][2] * di); o.w = f2bf(acc[i][3] * di);
            *((ushort4*)(G + (size_t)row * NC + tx * 4)) = o;
        }
    }
}

// NC=64 aggregation. One wave per node; lane = grp(3b)*8 + sub(3b).
// lane loads uint4 (8 bf16 cols at sub*8); 8 lanes cover a row; 8 edge rows
// per instruction. Merge partials via shfl_xor(8|16|32).
__global__ void agg64_kernel(const unsigned short* __restrict__ G,
                             const int* __restrict__ rowptr, const int* __restrict__ deg,
                             const unsigned short* __restrict__ cidx,
                             const float* __restrict__ dinv, const float* __restrict__ b,
                             unsigned short* __restrict__ Y, int M) {
    const int lane = threadIdx.x & 63;
    const int node = blockIdx.x * 4 + (threadIdx.x >> 6);
    if (node >= M) return;
    const int grp = lane >> 3;                 // 0..7 edge slot
    const int sub = lane & 7;                  // 0..7 col octet
    const int start = rowptr[node];
    const int cnt = deg[node];

    float a[8] = {0.f, 0.f, 0.f, 0.f, 0.f, 0.f, 0.f, 0.f};
    float c[8] = {0.f, 0.f, 0.f, 0.f, 0.f, 0.f, 0.f, 0.f};

    for (int base = 0; base < cnt; base += 64) {
        const int nthis = min(64, cnt - base);
        int myidx = (lane < nthis) ? (int)cidx[start + base + lane] : 0;
        int j = 0;
        for (; j + 16 <= nthis; j += 16) {
            int s0 = __shfl(myidx, j + grp, 64);
            int s1 = __shfl(myidx, j + 8 + grp, 64);
            uint4 v0 = *(const uint4*)(G + (size_t)s0 * 64 + sub * 8);
            uint4 v1 = *(const uint4*)(G + (size_t)s1 * 64 + sub * 8);
            acc_bf16x8(v0, a);
            acc_bf16x8(v1, c);
        }
        if (j + 8 <= nthis) {
            int s0 = __shfl(myidx, j + grp, 64);
            uint4 v0 = *(const uint4*)(G + (size_t)s0 * 64 + sub * 8);
            acc_bf16x8(v0, a);
            j += 8;
        }
        const int rem = nthis - j;             // 0..7
        if (grp < rem) {
            int s0 = __shfl(myidx, j + grp, 64);
            uint4 v0 = *(const uint4*)(G + (size_t)s0 * 64 + sub * 8);
            acc_bf16x8(v0, c);
        }
    }
#pragma unroll
    for (int k = 0; k < 8; ++k) a[k] += c[k];
#pragma unroll
    for (int k = 0; k < 8; ++k) {
        a[k] += __shfl_xor(a[k], 8, 64);
        a[k] += __shfl_xor(a[k], 16, 64);
        a[k] += __shfl_xor(a[k], 32, 64);
    }
    if (grp != 0) return;
    // self term + bias + relu + bf16 store (lanes 0..7)
    uint4 sv = *(const uint4*)(G + (size_t)node * 64 + sub * 8);
    float self[8];
    self[0] = bf2f((unsigned short)(sv.x & 0xffffu)); self[1] = bf2f((unsigned short)(sv.x >> 16));
    self[2] = bf2f((unsigned short)(sv.y & 0xffffu)); self[3] = bf2f((unsigned short)(sv.y >> 16));
    self[4] = bf2f((unsigned short)(sv.z & 0xffffu)); self[5] = bf2f((unsigned short)(sv.z >> 16));
    self[6] = bf2f((unsigned short)(sv.w & 0xffffu)); self[7] = bf2f((unsigned short)(sv.w >> 16));
    float4 b0 = *(const float4*)(b + sub * 8);
    float4 b1 = *(const float4*)(b + sub * 8 + 4);
    const float di = dinv[node];
    float v[8];
    v[0] = fmaxf((a[0] + self[0]) * di + b0.x, 0.f);
    v[1] = fmaxf((a[1] + self[1]) * di + b0.y, 0.f);
    v[2] = fmaxf((a[2] + self[2]) * di + b0.z, 0.f);
    v[3] = fmaxf((a[3] + self[3]) * di + b0.w, 0.f);
    v[4] = fmaxf((a[4] + self[4]) * di + b1.x, 0.f);
    v[5] = fmaxf((a[5] + self[5]) * di + b1.y, 0.f);
    v[6] = fmaxf((a[6] + self[6]) * di + b1.z, 0.f);
    v[7] = fmaxf((a[7] + self[7]) * di + b1.w, 0.f);
    uint4 o;
    o.x = pk2bf(v[0], v[1]); o.y = pk2bf(v[2], v[3]);
    o.z = pk2bf(v[4], v[5]); o.w = pk2bf(v[6], v[7]);
    *((uint4*)(Y + (size_t)node * 64 + sub * 8)) = o;
}

// NC=40 aggregation + fused log_softmax. lane = grp(2b)*16 + sub(4b);
// lane owns cols [sub*4, sub*4+4); 4 edge rows per instruction.
__global__ void agg40_lsm_kernel(const unsigned short* __restrict__ G,
                                 const int* __restrict__ rowptr, const int* __restrict__ deg,
                                 const unsigned short* __restrict__ cidx,
                                 const float* __restrict__ dinv, const float* __restrict__ b,
                                 float* __restrict__ Y, int M) {
    constexpr int NC = 40;
    constexpr int NQ = 10;
    const int lane = threadIdx.x & 63;
    const int node = blockIdx.x * 4 + (threadIdx.x >> 6);
    if (node >= M) return;
    const int grp = lane >> 4;                 // 0..3
    const int sub = lane & 15;                 // 0..15
    const bool act = (sub < NQ);
    const int start = rowptr[node];
    const int cnt = deg[node];

    float a[4] = {0.f, 0.f, 0.f, 0.f};
    float c[4] = {0.f, 0.f, 0.f, 0.f};

    for (int base = 0; base < cnt; base += 64) {
        const int nthis = min(64, cnt - base);
        int myidx = (lane < nthis) ? (int)cidx[start + base + lane] : 0;
        int j = 0;
        for (; j + 8 <= nthis; j += 8) {
            int s0 = __shfl(myidx, j + grp, 64);
            int s1 = __shfl(myidx, j + 4 + grp, 64);
            if (act) {
                uint2 v0 = *(const uint2*)(G + (size_t)s0 * NC + sub * 4);
                uint2 v1 = *(const uint2*)(G + (size_t)s1 * NC + sub * 4);
                acc_bf16x4(v0, a);
                acc_bf16x4(v1, c);
            }
        }
        if (j + 4 <= nthis) {
            int s0 = __shfl(myidx, j + grp, 64);
            if (act) {
                uint2 v0 = *(const uint2*)(G + (size_t)s0 * NC + sub * 4);
                acc_bf16x4(v0, a);
            }
            j += 4;
        }
        const int rem = nthis - j;             // 0..3
        if (grp < rem) {
            int s0 = __shfl(myidx, j + grp, 64);
            if (act) {
                uint2 v0 = *(const uint2*)(G + (size_t)s0 * NC + sub * 4);
                acc_bf16x4(v0, c);
            }
        }
    }
#pragma unroll
    for (int k = 0; k < 4; ++k) a[k] += c[k];
#pragma unroll
    for (int k = 0; k < 4; ++k) {
        a[k] += __shfl_xor(a[k], 16, 64);
        a[k] += __shfl_xor(a[k], 32, 64);
    }
    float v[4];
    {
        float self[4] = {0.f, 0.f, 0.f, 0.f};
        float4 bb = make_float4(0.f, 0.f, 0.f, 0.f);
        if (act) {
            uint2 sv = *(const uint2*)(G + (size_t)node * NC + sub * 4);
            self[0] = bf2f((unsigned short)(sv.x & 0xffffu));
            self[1] = bf2f((unsigned short)(sv.x >> 16));
            self[2] = bf2f((unsigned short)(sv.y & 0xffffu));
            self[3] = bf2f((unsigned short)(sv.y >> 16));
            bb = *(const float4*)(b + sub * 4);
        }
        const float di = dinv[node];
        v[0] = fmaxf((a[0] + self[0]) * di + bb.x, 0.f);
        v[1] = fmaxf((a[1] + self[1]) * di + bb.y, 0.f);
        v[2] = fmaxf((a[2] + self[2]) * di + bb.z, 0.f);
        v[3] = fmaxf((a[3] + self[3]) * di + bb.w, 0.f);
    }
    float m = act ? fmaxf(fmaxf(v[0], v[1]), fmaxf(v[2], v[3])) : -INFINITY;
#pragma unroll
    for (int o = 1; o < 16; o <<= 1) m = fmaxf(m, __shfl_xor(m, o, 64));
    float es = act ? (expf(v[0] - m) + expf(v[1] - m) + expf(v[2] - m) + expf(v[3] - m)) : 0.f;
#pragma unroll
    for (int o = 1; o < 16; o <<= 1) es += __shfl_xor(es, o, 64);
    const float ls = logf(es);
    if (act && grp == 0) {
        *((float4*)(Y + (size_t)node * NC + sub * 4)) =
            make_float4(v[0] - m - ls, v[1] - m - ls, v[2] - m - ls, v[3] - m - ls);
    }
}

extern "C" void kernel_launch(void* const* d_in, const int* in_sizes, int n_in,
                              void* d_out, int out_size, void* d_ws, size_t ws_size,
                              hipStream_t stream) {
    const float* x  = (const float*)d_in[0];
    const int*   ei = (const int*)d_in[1];        // [2, E] int32
    const float* W1 = (const float*)d_in[2];
    const float* b1 = (const float*)d_in[3];
    const float* W2 = (const float*)d_in[4];
    const float* b2 = (const float*)d_in[5];
    const float* W3 = (const float*)d_in[6];
    const float* b3 = (const float*)d_in[7];
    float* out = (float*)d_out;

    const int M  = in_sizes[0] / DF;              // 50000
    const int E  = in_sizes[1] / 2;               // 800000
    (void)ws_size; (void)n_in; (void)out_size;

    const int* src = ei;
    const int* dst = ei + E;

    const size_t Ma = ((size_t)M + 63) & ~63ull;
    const size_t Ea = ((size_t)E + 63) & ~63ull;

    // workspace layout
    int* deg    = (int*)d_ws;                            // Ma
    int* rowptr = deg + Ma;                              // Ma
    int* cursor = rowptr + Ma;                           // Ma
    int* bsum   = cursor + Ma;                           // 256
    unsigned short* cidx = (unsigned short*)(bsum + 256);        // Ea (u16)
    float* dinv = (float*)(cidx + Ea);                   // Ma
    unsigned short* G    = (unsigned short*)(dinv + Ma);         // Ma*64 (bf16)
    unsigned short* Bact = G + Ma * DF;                  // Ma*64 (bf16 activations)

    const int gN = (M + TB - 1) / TB;
    const int nb = gN;                   // scan blocks (196 <= 256)
    const int psize = (M + NPART - 1) / NPART;
    const int partGrd = NPART * 96;      // 8 partitions x 96 slices

    // --- CSR build + dinv (once, reused by all 3 layers) ---
    zero_int_kernel<<<gN, TB, 0, stream>>>(deg, M);
    count_deg_part_kernel<<<partGrd, TB, 0, stream>>>(dst, deg, E, psize);
    scan_block_kernel<<<nb, TB, 0, stream>>>(deg, rowptr, bsum, dinv, M);
    add_offsets_kernel<<<nb, TB, 0, stream>>>(rowptr, bsum, cursor, M, nb);
    fill_csr_part_kernel<<<partGrd, TB, 0, stream>>>(src, dst, cursor, cidx, E, psize);

    const dim3 gemmBlk(16, 16);
    const int  gemmGrd = (M + 63) / 64;
    const int  aggGrd  = (M + 3) / 4;

    // --- layer 1 ---
    gemm_kernel<64, float><<<gemmGrd, gemmBlk, 0, stream>>>(x, W1, dinv, G, M);
    agg64_kernel<<<aggGrd, TB, 0, stream>>>(G, rowptr, deg, cidx, dinv, b1, Bact, M);
    // --- layer 2 ---
    gemm_kernel<64, unsigned short><<<gemmGrd, gemmBlk, 0, stream>>>(Bact, W2, dinv, G, M);
    agg64_kernel<<<aggGrd, TB, 0, stream>>>(G, rowptr, deg, cidx, dinv, b2, Bact, M);
    // --- layer 3 (40 cols) + fused log_softmax ---
    gemm_kernel<40, unsigned short><<<gemmGrd, gemmBlk, 0, stream>>>(Bact, W3, dinv, G, M);
    agg40_lsm_kernel<<<aggGrd, TB, 0, stream>>>(G, rowptr, deg, cidx, dinv, b3, out, M);
}

// Round 8
// 215.432 us; speedup vs baseline: 1.1595x; 1.1595x over previous
//
#include <hip/hip_runtime.h>
#include <math.h>

// ---------------------------------------------------------------------------
// GCN, atomic-free aggregation via per-call CSR (bucket by dst):
//   deg count (dst-partitioned) -> block scan(+dinv) -> add_offsets (fused
//   bsum scan) -> fill (dst-partitioned, XCD-local, u16)          [once]
//   per layer: G = (X@W)*dinv[row]  (GEMM: 16-row tile, 1x4 per thread —
//              round-6 shape; round-7's 4x4 reg-blocking cratered occupancy
//              to 8.5% w/ 236 VGPR + 33KB LDS, 5x slower. Keep it simple.)
//              y[i] = relu( dinv[i]*(G[i] + sum_{e: dst=i} G[src_e]) + b )
//   layers 1-2 emit bf16 activations; layer 3 fuses log_softmax (fp32 out).
// agg64: one wave per node; lane=(grp<<3)|sub, lane loads uint4 (8 bf16 cols),
//   8 lanes cover a 128B row, 8 edge rows per instruction (1KiB/instr);
//   partials merged with shfl_xor(8|16|32).
// agg40: 16-lane rows (uint2), 4 edge rows/instr, fused log_softmax.
// cidx is uint16 (N_NODES=50000 < 65536).
// NOTE: no hipMemsetAsync — rocclr fillBuffer took 45.9us for 195KB in-graph.
// ---------------------------------------------------------------------------

#define DF 64
#define TB 256
#define NPART 8

__device__ __forceinline__ unsigned short f2bf(float f) {
    union { float f; unsigned u; } c; c.f = f;
    unsigned u = c.u;
    return (unsigned short)((u + 0x7fffu + ((u >> 16) & 1u)) >> 16);   // RNE
}
__device__ __forceinline__ float bf2f(unsigned short h) {
    union { unsigned u; float f; } c; c.u = ((unsigned)h) << 16;
    return c.f;
}
__device__ __forceinline__ unsigned pk2bf(float lo, float hi) {
    return (unsigned)f2bf(lo) | ((unsigned)f2bf(hi) << 16);
}
__device__ __forceinline__ void acc_bf16x8(uint4 v, float* a) {
    a[0] += bf2f((unsigned short)(v.x & 0xffffu));
    a[1] += bf2f((unsigned short)(v.x >> 16));
    a[2] += bf2f((unsigned short)(v.y & 0xffffu));
    a[3] += bf2f((unsigned short)(v.y >> 16));
    a[4] += bf2f((unsigned short)(v.z & 0xffffu));
    a[5] += bf2f((unsigned short)(v.z >> 16));
    a[6] += bf2f((unsigned short)(v.w & 0xffffu));
    a[7] += bf2f((unsigned short)(v.w >> 16));
}
__device__ __forceinline__ void acc_bf16x4(uint2 v, float* a) {
    a[0] += bf2f((unsigned short)(v.x & 0xffffu));
    a[1] += bf2f((unsigned short)(v.x >> 16));
    a[2] += bf2f((unsigned short)(v.y & 0xffffu));
    a[3] += bf2f((unsigned short)(v.y >> 16));
}

__global__ void zero_int_kernel(int* __restrict__ p, int n) {
    int i = blockIdx.x * blockDim.x + threadIdx.x;
    if (i < n) p[i] = 0;
}

__global__ void count_deg_part_kernel(const int* __restrict__ dst, int* __restrict__ deg,
                                      int e, int psize) {
    const int p   = blockIdx.x & (NPART - 1);
    const int sl  = blockIdx.x / NPART;
    const int nsl = gridDim.x / NPART;
    const int lo = p * psize, hi = lo + psize;
    for (int i = sl * TB + threadIdx.x; i < e; i += nsl * TB) {
        int d = dst[i];
        if (d >= lo && d < hi) atomicAdd(&deg[d], 1);
    }
}

// per-block exclusive scan of deg -> ex (partial), block totals -> bsum; also dinv
__global__ void scan_block_kernel(const int* __restrict__ deg, int* __restrict__ ex,
                                  int* __restrict__ bsum, float* __restrict__ dinv, int n) {
    __shared__ int s[TB];
    const int t = threadIdx.x;
    const int i = blockIdx.x * TB + t;
    int v = (i < n) ? deg[i] : 0;
    if (i < n) dinv[i] = rsqrtf((float)(v + 1));   // +1 self-loop
    s[t] = v; __syncthreads();
#pragma unroll
    for (int o = 1; o < TB; o <<= 1) {
        int u = (t >= o) ? s[t - o] : 0;
        __syncthreads();
        s[t] += u;
        __syncthreads();
    }
    if (i < n) ex[i] = s[t] - v;
    if (t == TB - 1) bsum[blockIdx.x] = s[TB - 1];
}

// each block redundantly scans bsum (nb <= 256) in LDS, then offsets its slice
__global__ void add_offsets_kernel(int* __restrict__ ex, const int* __restrict__ bsum,
                                   int* __restrict__ cursor, int n, int nb) {
    __shared__ int s[TB];
    const int t = threadIdx.x;
    int v = (t < nb) ? bsum[t] : 0;
    s[t] = v; __syncthreads();
#pragma unroll
    for (int o = 1; o < TB; o <<= 1) {
        int u = (t >= o) ? s[t - o] : 0;
        __syncthreads();
        s[t] += u;
        __syncthreads();
    }
    const int boff = (blockIdx.x > 0) ? s[blockIdx.x - 1] : 0;
    const int i = blockIdx.x * TB + t;
    if (i < n) {
        int r = ex[i] + boff;
        ex[i] = r;
        cursor[i] = r;
    }
}

__global__ void fill_csr_part_kernel(const int* __restrict__ src, const int* __restrict__ dst,
                                     int* __restrict__ cursor,
                                     unsigned short* __restrict__ cidx, int e, int psize) {
    const int p   = blockIdx.x & (NPART - 1);
    const int sl  = blockIdx.x / NPART;
    const int nsl = gridDim.x / NPART;
    const int lo = p * psize, hi = lo + psize;
    for (int i = sl * TB + threadIdx.x; i < e; i += nsl * TB) {
        int d = dst[i];
        if (d >= lo && d < hi) {
            int pos = atomicAdd(&cursor[d], 1);
            cidx[pos] = (unsigned short)src[i];
        }
    }
}

// G[M x NC](bf16) = (X[M x 64] @ W[64 x NC]) * dinv[row].
// Block (16,16): 16 rows/block, each thread computes 1 row x 4 cols (float4 W).
// Low VGPR + ~21KB LDS -> high occupancy; this beat 4x4 reg-blocking 5x.
template <int NC, typename TIN>
__global__ __launch_bounds__(256) void gemm_kernel(const TIN* __restrict__ X,
                                                   const float* __restrict__ W,
                                                   const float* __restrict__ dinv,
                                                   unsigned short* __restrict__ G, int M) {
    __shared__ float Ws[64 * NC];
    __shared__ float Xs[16][65];
    const int tx = threadIdx.x;            // 0..15 col group
    const int ty = threadIdx.y;            // 0..15 row
    const int tid = ty * 16 + tx;
    for (int i = tid; i < 16 * NC; i += 256)
        ((float4*)Ws)[i] = ((const float4*)W)[i];
    const int row0 = blockIdx.x * 16;
    {   // stage 16 rows of X
        if (sizeof(TIN) == 4) {
            const float* Xf = (const float*)X;
            int r = tid / 16, c4 = tid % 16;      // 256 threads x float4
            float4 v = (row0 + r < M) ? ((const float4*)(Xf + (size_t)(row0 + r) * 64))[c4]
                                      : make_float4(0.f, 0.f, 0.f, 0.f);
            Xs[r][c4 * 4 + 0] = v.x; Xs[r][c4 * 4 + 1] = v.y;
            Xs[r][c4 * 4 + 2] = v.z; Xs[r][c4 * 4 + 3] = v.w;
        } else if (tid < 128) {                   // 128 threads x uint4 (8 bf16)
            const unsigned short* Xh = (const unsigned short*)X;
            int r = tid >> 3, s = tid & 7;
            uint4 v = (row0 + r < M)
                        ? *(const uint4*)(Xh + (size_t)(row0 + r) * 64 + s * 8)
                        : make_uint4(0, 0, 0, 0);
            Xs[r][s * 8 + 0] = bf2f((unsigned short)(v.x & 0xffffu));
            Xs[r][s * 8 + 1] = bf2f((unsigned short)(v.x >> 16));
            Xs[r][s * 8 + 2] = bf2f((unsigned short)(v.y & 0xffffu));
            Xs[r][s * 8 + 3] = bf2f((unsigned short)(v.y >> 16));
            Xs[r][s * 8 + 4] = bf2f((unsigned short)(v.z & 0xffffu));
            Xs[r][s * 8 + 5] = bf2f((unsigned short)(v.z >> 16));
            Xs[r][s * 8 + 6] = bf2f((unsigned short)(v.w & 0xffffu));
            Xs[r][s * 8 + 7] = bf2f((unsigned short)(v.w >> 16));
        }
    }
    __syncthreads();
    const int row = row0 + ty;
    const int c0 = tx * 4;
    if (row < M && c0 < NC) {
        float a0 = 0.f, a1 = 0.f, a2 = 0.f, a3 = 0.f;
#pragma unroll
        for (int k = 0; k < 64; ++k) {
            float xk = Xs[ty][k];
            float4 w = ((const float4*)(Ws + (size_t)k * NC))[tx];
            a0 += xk * w.x; a1 += xk * w.y; a2 += xk * w.z; a3 += xk * w.w;
        }
        float di = dinv[row];
        ushort4 o;
        o.x = f2bf(a0 * di); o.y = f2bf(a1 * di);
        o.z = f2bf(a2 * di); o.w = f2bf(a3 * di);
        *((ushort4*)(G + (size_t)row * NC + c0)) = o;
    }
}

// NC=64 aggregation. One wave per node; lane = grp(3b)*8 + sub(3b).
// lane loads uint4 (8 bf16 cols at sub*8); 8 lanes cover a row; 8 edge rows
// per instruction. Merge partials via shfl_xor(8|16|32).
__global__ void agg64_kernel(const unsigned short* __restrict__ G,
                             const int* __restrict__ rowptr, const int* __restrict__ deg,
                             const unsigned short* __restrict__ cidx,
                             const float* __restrict__ dinv, const float* __restrict__ b,
                             unsigned short* __restrict__ Y, int M) {
    const int lane = threadIdx.x & 63;
    const int node = blockIdx.x * 4 + (threadIdx.x >> 6);
    if (node >= M) return;
    const int grp = lane >> 3;                 // 0..7 edge slot
    const int sub = lane & 7;                  // 0..7 col octet
    const int start = rowptr[node];
    const int cnt = deg[node];

    float a[8] = {0.f, 0.f, 0.f, 0.f, 0.f, 0.f, 0.f, 0.f};
    float c[8] = {0.f, 0.f, 0.f, 0.f, 0.f, 0.f, 0.f, 0.f};

    for (int base = 0; base < cnt; base += 64) {
        const int nthis = min(64, cnt - base);
        int myidx = (lane < nthis) ? (int)cidx[start + base + lane] : 0;
        int j = 0;
        for (; j + 16 <= nthis; j += 16) {
            int s0 = __shfl(myidx, j + grp, 64);
            int s1 = __shfl(myidx, j + 8 + grp, 64);
            uint4 v0 = *(const uint4*)(G + (size_t)s0 * 64 + sub * 8);
            uint4 v1 = *(const uint4*)(G + (size_t)s1 * 64 + sub * 8);
            acc_bf16x8(v0, a);
            acc_bf16x8(v1, c);
        }
        if (j + 8 <= nthis) {
            int s0 = __shfl(myidx, j + grp, 64);
            uint4 v0 = *(const uint4*)(G + (size_t)s0 * 64 + sub * 8);
            acc_bf16x8(v0, a);
            j += 8;
        }
        const int rem = nthis - j;             // 0..7
        if (grp < rem) {
            int s0 = __shfl(myidx, j + grp, 64);
            uint4 v0 = *(const uint4*)(G + (size_t)s0 * 64 + sub * 8);
            acc_bf16x8(v0, c);
        }
    }
#pragma unroll
    for (int k = 0; k < 8; ++k) a[k] += c[k];
#pragma unroll
    for (int k = 0; k < 8; ++k) {
        a[k] += __shfl_xor(a[k], 8, 64);
        a[k] += __shfl_xor(a[k], 16, 64);
        a[k] += __shfl_xor(a[k], 32, 64);
    }
    if (grp != 0) return;
    // self term + bias + relu + bf16 store (lanes 0..7)
    uint4 sv = *(const uint4*)(G + (size_t)node * 64 + sub * 8);
    float self[8];
    self[0] = bf2f((unsigned short)(sv.x & 0xffffu)); self[1] = bf2f((unsigned short)(sv.x >> 16));
    self[2] = bf2f((unsigned short)(sv.y & 0xffffu)); self[3] = bf2f((unsigned short)(sv.y >> 16));
    self[4] = bf2f((unsigned short)(sv.z & 0xffffu)); self[5] = bf2f((unsigned short)(sv.z >> 16));
    self[6] = bf2f((unsigned short)(sv.w & 0xffffu)); self[7] = bf2f((unsigned short)(sv.w >> 16));
    float4 b0 = *(const float4*)(b + sub * 8);
    float4 b1 = *(const float4*)(b + sub * 8 + 4);
    const float di = dinv[node];
    float v[8];
    v[0] = fmaxf((a[0] + self[0]) * di + b0.x, 0.f);
    v[1] = fmaxf((a[1] + self[1]) * di + b0.y, 0.f);
    v[2] = fmaxf((a[2] + self[2]) * di + b0.z, 0.f);
    v[3] = fmaxf((a[3] + self[3]) * di + b0.w, 0.f);
    v[4] = fmaxf((a[4] + self[4]) * di + b1.x, 0.f);
    v[5] = fmaxf((a[5] + self[5]) * di + b1.y, 0.f);
    v[6] = fmaxf((a[6] + self[6]) * di + b1.z, 0.f);
    v[7] = fmaxf((a[7] + self[7]) * di + b1.w, 0.f);
    uint4 o;
    o.x = pk2bf(v[0], v[1]); o.y = pk2bf(v[2], v[3]);
    o.z = pk2bf(v[4], v[5]); o.w = pk2bf(v[6], v[7]);
    *((uint4*)(Y + (size_t)node * 64 + sub * 8)) = o;
}

// NC=40 aggregation + fused log_softmax. lane = grp(2b)*16 + sub(4b);
// lane owns cols [sub*4, sub*4+4); 4 edge rows per instruction.
__global__ void agg40_lsm_kernel(const unsigned short* __restrict__ G,
                                 const int* __restrict__ rowptr, const int* __restrict__ deg,
                                 const unsigned short* __restrict__ cidx,
                                 const float* __restrict__ dinv, const float* __restrict__ b,
                                 float* __restrict__ Y, int M) {
    constexpr int NC = 40;
    constexpr int NQ = 10;
    const int lane = threadIdx.x & 63;
    const int node = blockIdx.x * 4 + (threadIdx.x >> 6);
    if (node >= M) return;
    const int grp = lane >> 4;                 // 0..3
    const int sub = lane & 15;                 // 0..15
    const bool act = (sub < NQ);
    const int start = rowptr[node];
    const int cnt = deg[node];

    float a[4] = {0.f, 0.f, 0.f, 0.f};
    float c[4] = {0.f, 0.f, 0.f, 0.f};

    for (int base = 0; base < cnt; base += 64) {
        const int nthis = min(64, cnt - base);
        int myidx = (lane < nthis) ? (int)cidx[start + base + lane] : 0;
        int j = 0;
        for (; j + 8 <= nthis; j += 8) {
            int s0 = __shfl(myidx, j + grp, 64);
            int s1 = __shfl(myidx, j + 4 + grp, 64);
            if (act) {
                uint2 v0 = *(const uint2*)(G + (size_t)s0 * NC + sub * 4);
                uint2 v1 = *(const uint2*)(G + (size_t)s1 * NC + sub * 4);
                acc_bf16x4(v0, a);
                acc_bf16x4(v1, c);
            }
        }
        if (j + 4 <= nthis) {
            int s0 = __shfl(myidx, j + grp, 64);
            if (act) {
                uint2 v0 = *(const uint2*)(G + (size_t)s0 * NC + sub * 4);
                acc_bf16x4(v0, a);
            }
            j += 4;
        }
        const int rem = nthis - j;             // 0..3
        if (grp < rem) {
            int s0 = __shfl(myidx, j + grp, 64);
            if (act) {
                uint2 v0 = *(const uint2*)(G + (size_t)s0 * NC + sub * 4);
                acc_bf16x4(v0, c);
            }
        }
    }
#pragma unroll
    for (int k = 0; k < 4; ++k) a[k] += c[k];
#pragma unroll
    for (int k = 0; k < 4; ++k) {
        a[k] += __shfl_xor(a[k], 16, 64);
        a[k] += __shfl_xor(a[k], 32, 64);
    }
    float v[4];
    {
        float self[4] = {0.f, 0.f, 0.f, 0.f};
        float4 bb = make_float4(0.f, 0.f, 0.f, 0.f);
        if (act) {
            uint2 sv = *(const uint2*)(G + (size_t)node * NC + sub * 4);
            self[0] = bf2f((unsigned short)(sv.x & 0xffffu));
            self[1] = bf2f((unsigned short)(sv.x >> 16));
            self[2] = bf2f((unsigned short)(sv.y & 0xffffu));
            self[3] = bf2f((unsigned short)(sv.y >> 16));
            bb = *(const float4*)(b + sub * 4);
        }
        const float di = dinv[node];
        v[0] = fmaxf((a[0] + self[0]) * di + bb.x, 0.f);
        v[1] = fmaxf((a[1] + self[1]) * di + bb.y, 0.f);
        v[2] = fmaxf((a[2] + self[2]) * di + bb.z, 0.f);
        v[3] = fmaxf((a[3] + self[3]) * di + bb.w, 0.f);
    }
    float m = act ? fmaxf(fmaxf(v[0], v[1]), fmaxf(v[2], v[3])) : -INFINITY;
#pragma unroll
    for (int o = 1; o < 16; o <<= 1) m = fmaxf(m, __shfl_xor(m, o, 64));
    float es = act ? (expf(v[0] - m) + expf(v[1] - m) + expf(v[2] - m) + expf(v[3] - m)) : 0.f;
#pragma unroll
    for (int o = 1; o < 16; o <<= 1) es += __shfl_xor(es, o, 64);
    const float ls = logf(es);
    if (act && grp == 0) {
        *((float4*)(Y + (size_t)node * NC + sub * 4)) =
            make_float4(v[0] - m - ls, v[1] - m - ls, v[2] - m - ls, v[3] - m - ls);
    }
}

extern "C" void kernel_launch(void* const* d_in, const int* in_sizes, int n_in,
                              void* d_out, int out_size, void* d_ws, size_t ws_size,
                              hipStream_t stream) {
    const float* x  = (const float*)d_in[0];
    const int*   ei = (const int*)d_in[1];        // [2, E] int32
    const float* W1 = (const float*)d_in[2];
    const float* b1 = (const float*)d_in[3];
    const float* W2 = (const float*)d_in[4];
    const float* b2 = (const float*)d_in[5];
    const float* W3 = (const float*)d_in[6];
    const float* b3 = (const float*)d_in[7];
    float* out = (float*)d_out;

    const int M  = in_sizes[0] / DF;              // 50000
    const int E  = in_sizes[1] / 2;               // 800000
    (void)ws_size; (void)n_in; (void)out_size;

    const int* src = ei;
    const int* dst = ei + E;

    const size_t Ma = ((size_t)M + 63) & ~63ull;
    const size_t Ea = ((size_t)E + 63) & ~63ull;

    // workspace layout
    int* deg    = (int*)d_ws;                            // Ma
    int* rowptr = deg + Ma;                              // Ma
    int* cursor = rowptr + Ma;                           // Ma
    int* bsum   = cursor + Ma;                           // 256
    unsigned short* cidx = (unsigned short*)(bsum + 256);        // Ea (u16)
    float* dinv = (float*)(cidx + Ea);                   // Ma
    unsigned short* G    = (unsigned short*)(dinv + Ma);         // Ma*64 (bf16)
    unsigned short* Bact = G + Ma * DF;                  // Ma*64 (bf16 activations)

    const int gN = (M + TB - 1) / TB;
    const int nb = gN;                   // scan blocks (196 <= 256)
    const int psize = (M + NPART - 1) / NPART;
    const int partGrd = NPART * 96;      // 8 partitions x 96 slices

    // --- CSR build + dinv (once, reused by all 3 layers) ---
    zero_int_kernel<<<gN, TB, 0, stream>>>(deg, M);
    count_deg_part_kernel<<<partGrd, TB, 0, stream>>>(dst, deg, E, psize);
    scan_block_kernel<<<nb, TB, 0, stream>>>(deg, rowptr, bsum, dinv, M);
    add_offsets_kernel<<<nb, TB, 0, stream>>>(rowptr, bsum, cursor, M, nb);
    fill_csr_part_kernel<<<partGrd, TB, 0, stream>>>(src, dst, cursor, cidx, E, psize);

    const dim3 gemmBlk(16, 16);
    const int  gemmGrd = (M + 15) / 16;
    const int  aggGrd  = (M + 3) / 4;

    // --- layer 1 ---
    gemm_kernel<64, float><<<gemmGrd, gemmBlk, 0, stream>>>(x, W1, dinv, G, M);
    agg64_kernel<<<aggGrd, TB, 0, stream>>>(G, rowptr, deg, cidx, dinv, b1, Bact, M);
    // --- layer 2 ---
    gemm_kernel<64, unsigned short><<<gemmGrd, gemmBlk, 0, stream>>>(Bact, W2, dinv, G, M);
    agg64_kernel<<<aggGrd, TB, 0, stream>>>(G, rowptr, deg, cidx, dinv, b2, Bact, M);
    // --- layer 3 (40 cols) + fused log_softmax ---
    gemm_kernel<40, unsigned short><<<gemmGrd, gemmBlk, 0, stream>>>(Bact, W3, dinv, G, M);
    agg40_lsm_kernel<<<aggGrd, TB, 0, stream>>>(G, rowptr, deg, cidx, dinv, b3, out, M);
}